// Round 8
// baseline (429.455 us; speedup 1.0000x reference)
//
#include <hip/hip_runtime.h>
#include <cstdint>
#include <cstddef>

#define NN 50000
#define NE 800000
static constexpr int IN_F = 512;
static constexpr int HID  = 256;
static constexpr int OUTF = 128;

typedef __attribute__((ext_vector_type(8))) _Float16 half8;
typedef __attribute__((ext_vector_type(4))) _Float16 half4v;
typedef __attribute__((ext_vector_type(2))) _Float16 half2v;
typedef __attribute__((ext_vector_type(4))) float f32x4;

// ---------------- graph preprocessing ----------------

__global__ void k_degree(const int* __restrict__ src, const int* __restrict__ dst,
                         int* __restrict__ deg_out, int* __restrict__ deg_in, int E) {
  int e = blockIdx.x * blockDim.x + threadIdx.x;
  if (e < E) {
    atomicAdd(&deg_out[src[e]], 1);
    atomicAdd(&deg_in[dst[e]], 1);
  }
}

__global__ void k_norm(const int* __restrict__ deg_out, const int* __restrict__ deg_in,
                       float* __restrict__ norm_src, float* __restrict__ norm_dst, int N) {
  int i = blockIdx.x * blockDim.x + threadIdx.x;
  if (i < N) {
    int dO = deg_out[i]; if (dO < 1) dO = 1;
    int dI = deg_in[i];  if (dI < 1) dI = 1;
    norm_src[i] = rsqrtf((float)dO);
    norm_dst[i] = rsqrtf((float)dI);
  }
}

__global__ void k_scan1(const int* __restrict__ deg_in, int* __restrict__ excl,
                        int* __restrict__ bsums, int N) {
  __shared__ int s[512];
  int t = threadIdx.x;
  int g = blockIdx.x * 512 + t;
  int v = (g < N) ? deg_in[g] : 0;
  s[t] = v;
  __syncthreads();
  for (int off = 1; off < 512; off <<= 1) {
    int add = (t >= off) ? s[t - off] : 0;
    __syncthreads();
    s[t] += add;
    __syncthreads();
  }
  if (g < N) excl[g] = s[t] - v;
  if (t == 511) bsums[blockIdx.x] = s[511];
}

__global__ void k_scan2(int* __restrict__ bsums, int nb) {
  __shared__ int s[128];
  int t = threadIdx.x;
  int v = (t < nb) ? bsums[t] : 0;
  s[t] = v;
  __syncthreads();
  for (int off = 1; off < 128; off <<= 1) {
    int add = (t >= off) ? s[t - off] : 0;
    __syncthreads();
    s[t] += add;
    __syncthreads();
  }
  if (t < nb) bsums[t] = s[t] - v;
}

__global__ void k_scan3(int* __restrict__ row_off, const int* __restrict__ bsums,
                        int N, int E) {
  int g = blockIdx.x * blockDim.x + threadIdx.x;
  if (g < N) row_off[g] += bsums[g >> 9];
  if (g == 0) row_off[N] = E;
}

__global__ void k_fill(const int* __restrict__ src, const int* __restrict__ dst,
                       const int* __restrict__ row_off, int* __restrict__ cursor,
                       int* __restrict__ ssrc, int E) {
  int e = blockIdx.x * blockDim.x + threadIdx.x;
  if (e < E) {
    int d = dst[e];
    int pos = atomicAdd(&cursor[d], 1);
    ssrc[row_off[d] + pos] = src[e];
  }
}

// ---------------- weight transpose+cvt: W[K][N] fp32 -> WT[N][K] fp16 ----------------
__global__ void k_convW(const float* __restrict__ W, _Float16* __restrict__ WT,
                        int K, int N) {
  int t = blockIdx.x * blockDim.x + threadIdx.x;
  if (t >= K * N) return;
  int n = t / K, k = t - n * K;
  WT[t] = (_Float16)W[(size_t)k * N + n];
}

// ---------------- fp16 MFMA GEMM ----------------
// C[M][N](fp16) = (A * rowscale?) @ B.  B pre-cvt as BT[N][K] fp16.
// A: fp32 (AF32: cvt-in-staging) or fp16 (direct global_load_lds).
// BM=64, BN=128, BK=32; 4 waves, wave-tile 32x64 (acc[2][4]); LDS 24KB ->
// 6 blocks/CU = 24 waves/CU (grid-parallelism was the round-5 bottleneck).
template <bool AF32, bool SCALE>
__launch_bounds__(256, 6)
__global__ void k_gemm_f16(const void* __restrict__ Ap,
                           const _Float16* __restrict__ BT,
                           const float* __restrict__ rowscale,
                           _Float16* __restrict__ C, int M, int N, int K) {
  __shared__ uint4 sA[2][256];  // 4 frags x 64 chunks x 16B = 4KB/buf
  __shared__ uint4 sB[2][512];  // 8 frags x 64 chunks x 16B = 8KB/buf

  const int tid = threadIdx.x;
  const int wid = tid >> 6, lane = tid & 63;
  const int bm = blockIdx.x * 64, bn = blockIdx.y * 128;
  const int wrow = wid >> 1, wcol = wid & 1;

  const _Float16* Af16 = (const _Float16*)Ap;
  const float* Af32 = (const float*)Ap;

  // fp32 A staging: 4 frags x 64 chunks = 256 chunks, exactly 1 per thread.
  // chunk c: frag f=c>>6, role r=c&63 holds A[bm+f*16+(r&15)][k0+(r>>4)*8..+8].
  const float* pa = nullptr;
  float sc = 1.f;
  if constexpr (AF32) {
    const int f = tid >> 6, r = tid & 63;
    int g = bm + f * 16 + (r & 15); if (g > M - 1) g = M - 1;
    if constexpr (SCALE) sc = rowscale[g];
    pa = Af32 + (size_t)g * K + (r >> 4) * 8;
  }

  float4 av0, av1;
  auto loadA32 = [&](int k0) {
    av0 = *(const float4*)(pa + k0);
    av1 = *(const float4*)(pa + k0 + 4);
  };
  auto cvtWriteA = [&](int buf) {
    float fv[8] = {av0.x, av0.y, av0.z, av0.w, av1.x, av1.y, av1.z, av1.w};
    union { _Float16 h[8]; uint4 q; } pk;
#pragma unroll
    for (int i = 0; i < 8; ++i)
      pk.h[i] = (_Float16)(SCALE ? fv[i] * sc : fv[i]);
    sA[buf][tid] = pk.q;  // linear b128 write: conflict-free
  };
  // fp16 A staging: 4 global_load_lds (1KB each), 1 per wave.
  auto stageA16 = [&](int buf, int k0) {
    const int f = wid;  // wave-uniform frag 0..3
    int g = bm + f * 16 + (lane & 15); if (g > M - 1) g = M - 1;
    const _Float16* s = Af16 + (size_t)g * K + k0 + (lane >> 4) * 8;
    __builtin_amdgcn_global_load_lds(
        (const __attribute__((address_space(1))) unsigned int*)s,
        (__attribute__((address_space(3))) unsigned int*)&sA[buf][f * 64], 16, 0, 0);
  };
  auto stageB = [&](int buf, int k0) {
#pragma unroll
    for (int i = 0; i < 2; ++i) {
      const int f = wid * 2 + i;  // wave-uniform frag 0..7
      const _Float16* s = BT + (size_t)(bn + f * 16 + (lane & 15)) * K + k0 + (lane >> 4) * 8;
      __builtin_amdgcn_global_load_lds(
          (const __attribute__((address_space(1))) unsigned int*)s,
          (__attribute__((address_space(3))) unsigned int*)&sB[buf][f * 64], 16, 0, 0);
    }
  };

  f32x4 acc[2][4] = {};
  auto mfmaPhase = [&](int buf) {
    half8 ah[2], bh[4];
#pragma unroll
    for (int m = 0; m < 2; ++m)
      ah[m] = *(const half8*)&sA[buf][(wrow * 2 + m) * 64 + lane];
#pragma unroll
    for (int n = 0; n < 4; ++n)
      bh[n] = *(const half8*)&sB[buf][(wcol * 4 + n) * 64 + lane];
#pragma unroll
    for (int m = 0; m < 2; ++m)
#pragma unroll
      for (int n = 0; n < 4; ++n)
        acc[m][n] = __builtin_amdgcn_mfma_f32_16x16x32_f16(ah[m], bh[n], acc[m][n], 0, 0, 0);
  };

  const int nt = K >> 5;
  if constexpr (AF32) loadA32(0); else stageA16(0, 0);
  stageB(0, 0);
  if constexpr (AF32) cvtWriteA(0);
  __syncthreads();
  for (int t = 0; t < nt; ++t) {
    const int cur = t & 1;
    const bool more = (t + 1 < nt);
    if (more) {
      if constexpr (AF32) loadA32((t + 1) << 5); else stageA16(cur ^ 1, (t + 1) << 5);
      stageB(cur ^ 1, (t + 1) << 5);
    }
    mfmaPhase(cur);
    if (more) { if constexpr (AF32) cvtWriteA(cur ^ 1); }
    __syncthreads();
  }

  // epilogue: C/D frag mapping col=lane&15, row=(lane>>4)*4+reg (m89-verified)
#pragma unroll
  for (int m = 0; m < 2; ++m) {
    const int rb = bm + wrow * 32 + m * 16 + (lane >> 4) * 4;
#pragma unroll
    for (int r = 0; r < 4; ++r) {
      const int gm = rb + r;
      if (gm < M) {
        _Float16* cp = C + (size_t)gm * N + bn + wcol * 64 + (lane & 15);
#pragma unroll
        for (int n = 0; n < 4; ++n) cp[n * 16] = (_Float16)acc[m][n][r];
      }
    }
  }
}

// ---------------- CSR aggregation (one wave per dst node, fp16 gather) ----------------
// out[n] = [oscale *] act( sum_e H[ssrc[e]] * norm_dst[n] + bias )
template <int F, bool RELU, bool OSCALE, bool OUT16>
__launch_bounds__(256)
__global__ void k_agg16(const _Float16* __restrict__ H, const int* __restrict__ row_off,
                        const int* __restrict__ ssrc, const float* __restrict__ norm_dst,
                        const float* __restrict__ bias, const float* __restrict__ oscale,
                        void* __restrict__ outp, int N) {
  int wid = (blockIdx.x * 256 + threadIdx.x) >> 6;
  int lane = threadIdx.x & 63;
  if (wid >= N) return;
  int beg = row_off[wid], end = row_off[wid + 1];
  float nd = norm_dst[wid];

  if constexpr (F == 256) {
    float a0[4] = {}, a1[4] = {}, a2[4] = {}, a3[4] = {};
    int e = beg;
    for (; e + 4 <= end; e += 4) {
      int s0 = ssrc[e], s1 = ssrc[e + 1], s2 = ssrc[e + 2], s3 = ssrc[e + 3];
      half4v v0 = *(const half4v*)(H + (size_t)s0 * 256 + lane * 4);
      half4v v1 = *(const half4v*)(H + (size_t)s1 * 256 + lane * 4);
      half4v v2 = *(const half4v*)(H + (size_t)s2 * 256 + lane * 4);
      half4v v3 = *(const half4v*)(H + (size_t)s3 * 256 + lane * 4);
#pragma unroll
      for (int i = 0; i < 4; ++i) {
        a0[i] += (float)v0[i]; a1[i] += (float)v1[i];
        a2[i] += (float)v2[i]; a3[i] += (float)v3[i];
      }
    }
    for (; e < end; ++e) {
      half4v v = *(const half4v*)(H + (size_t)ssrc[e] * 256 + lane * 4);
#pragma unroll
      for (int i = 0; i < 4; ++i) a0[i] += (float)v[i];
    }
    const float4 bb = *(const float4*)(bias + lane * 4);
    float bv[4] = {bb.x, bb.y, bb.z, bb.w};
    float o[4];
#pragma unroll
    for (int i = 0; i < 4; ++i) {
      o[i] = fmaf(a0[i] + a1[i] + a2[i] + a3[i], nd, bv[i]);
      if (RELU) o[i] = fmaxf(o[i], 0.f);
    }
    if (OSCALE) {
      float os = oscale[wid];
#pragma unroll
      for (int i = 0; i < 4; ++i) o[i] *= os;
    }
    if constexpr (OUT16) {
      union { _Float16 h[4]; uint2 q; } pk;
#pragma unroll
      for (int i = 0; i < 4; ++i) pk.h[i] = (_Float16)o[i];
      *(uint2*)((_Float16*)outp + (size_t)wid * 256 + lane * 4) = pk.q;
    } else {
      *(float4*)((float*)outp + (size_t)wid * 256 + lane * 4) =
          make_float4(o[0], o[1], o[2], o[3]);
    }
  } else {  // F == 128
    float a0[2] = {}, a1[2] = {}, a2[2] = {}, a3[2] = {};
    int e = beg;
    for (; e + 4 <= end; e += 4) {
      int s0 = ssrc[e], s1 = ssrc[e + 1], s2 = ssrc[e + 2], s3 = ssrc[e + 3];
      half2v v0 = *(const half2v*)(H + (size_t)s0 * 128 + lane * 2);
      half2v v1 = *(const half2v*)(H + (size_t)s1 * 128 + lane * 2);
      half2v v2 = *(const half2v*)(H + (size_t)s2 * 128 + lane * 2);
      half2v v3 = *(const half2v*)(H + (size_t)s3 * 128 + lane * 2);
#pragma unroll
      for (int i = 0; i < 2; ++i) {
        a0[i] += (float)v0[i]; a1[i] += (float)v1[i];
        a2[i] += (float)v2[i]; a3[i] += (float)v3[i];
      }
    }
    for (; e < end; ++e) {
      half2v v = *(const half2v*)(H + (size_t)ssrc[e] * 128 + lane * 2);
#pragma unroll
      for (int i = 0; i < 2; ++i) a0[i] += (float)v[i];
    }
    const float2 bb = *(const float2*)(bias + lane * 2);
    float bv[2] = {bb.x, bb.y};
    float o[2];
#pragma unroll
    for (int i = 0; i < 2; ++i) {
      o[i] = fmaf(a0[i] + a1[i] + a2[i] + a3[i], nd, bv[i]);
      if (RELU) o[i] = fmaxf(o[i], 0.f);
    }
    if (OSCALE) {
      float os = oscale[wid];
#pragma unroll
      for (int i = 0; i < 2; ++i) o[i] *= os;
    }
    if constexpr (OUT16) {
      union { _Float16 h[2]; unsigned q; } pk;
      pk.h[0] = (_Float16)o[0]; pk.h[1] = (_Float16)o[1];
      *(unsigned*)((_Float16*)outp + (size_t)wid * 128 + lane * 2) = pk.q;
    } else {
      *(float2*)((float*)outp + (size_t)wid * 128 + lane * 2) = make_float2(o[0], o[1]);
    }
  }
}

// ---------------- launch ----------------

extern "C" void kernel_launch(void* const* d_in, const int* in_sizes, int n_in,
                              void* d_out, int out_size, void* d_ws, size_t ws_size,
                              hipStream_t stream) {
  const float* X  = (const float*)d_in[0];
  const float* W1 = (const float*)d_in[1];
  const float* b1 = (const float*)d_in[2];
  const float* W2 = (const float*)d_in[3];
  const float* b2 = (const float*)d_in[4];
  const int* src  = (const int*)d_in[5];
  const int* dst  = (const int*)d_in[6];
  float* out = (float*)d_out;

  char* p = (char*)d_ws;
  auto alloc = [&](size_t bytes) -> char* {
    char* r = p;
    p += (bytes + 255) & ~(size_t)255;
    return r;
  };
  _Float16* H1pre  = (_Float16*)alloc((size_t)NN * HID * 2);   // layer-1 pre-agg
  _Float16* H1post = (_Float16*)alloc((size_t)NN * HID * 2);   // relu(...)*nsrc
  _Float16* H2pre  = H1pre;                                    // reuse
  _Float16* W1T = (_Float16*)alloc((size_t)HID * IN_F * 2);
  _Float16* W2T = (_Float16*)alloc((size_t)OUTF * HID * 2);
  int* deg_out  = (int*)alloc((size_t)NN * 4);
  int* deg_in   = (int*)alloc((size_t)NN * 4);
  int* cursor   = (int*)alloc((size_t)NN * 4);
  int* row_off  = (int*)alloc((size_t)(NN + 1) * 4);
  int* bsums    = (int*)alloc(512);
  float* nsrc   = (float*)alloc((size_t)NN * 4);
  float* ndst   = (float*)alloc((size_t)NN * 4);
  int* ssrc     = (int*)alloc((size_t)NE * 4);

  hipMemsetAsync(deg_out, 0, (size_t)((char*)row_off - (char*)deg_out), stream);

  k_degree<<<(NE + 255) / 256, 256, 0, stream>>>(src, dst, deg_out, deg_in, NE);
  k_norm<<<(NN + 255) / 256, 256, 0, stream>>>(deg_out, deg_in, nsrc, ndst, NN);

  int nb = (NN + 511) / 512;
  k_scan1<<<nb, 512, 0, stream>>>(deg_in, row_off, bsums, NN);
  k_scan2<<<1, 128, 0, stream>>>(bsums, nb);
  k_scan3<<<(NN + 255) / 256, 256, 0, stream>>>(row_off, bsums, NN, NE);
  k_fill<<<(NE + 255) / 256, 256, 0, stream>>>(src, dst, row_off, cursor, ssrc, NE);

  k_convW<<<(IN_F * HID + 255) / 256, 256, 0, stream>>>(W1, W1T, IN_F, HID);
  k_convW<<<(HID * OUTF + 255) / 256, 256, 0, stream>>>(W2, W2T, HID, OUTF);

  // layer 1: H1pre = f16[(X*nsrc)@W1]; H1post = f16[relu(agg*ndst + b1)*nsrc]
  dim3 g1((NN + 63) / 64, HID / 128);
  k_gemm_f16<true, true><<<g1, 256, 0, stream>>>(X, W1T, nsrc, H1pre, NN, HID, IN_F);
  k_agg16<256, true, true, true><<<(NN * 64 + 255) / 256, 256, 0, stream>>>(
      H1pre, row_off, ssrc, ndst, b1, nsrc, H1post, NN);

  // layer 2: H2pre = f16[H1post@W2]; out = agg*ndst + b2 (fp32)
  dim3 g2((NN + 63) / 64, OUTF / 128);
  k_gemm_f16<false, false><<<g2, 256, 0, stream>>>(H1post, W2T, nullptr, H2pre, NN, OUTF, HID);
  k_agg16<128, false, false, false><<<(NN * 64 + 255) / 256, 256, 0, stream>>>(
      H2pre, row_off, ssrc, ndst, b2, nullptr, out, NN);
}